// Round 1
// baseline (61.783 us; speedup 1.0000x reference)
//
#include <hip/hip_runtime.h>

// Decoder: piecewise-linear curve eval.
// segment_x, segment_y: [B=8, N+1=33] fp32. Output: [B, S=196608] fp32.
//
// Semantics (proven equivalent to the reference masked-sum):
//  1) fixed knots = inclusive running-max scan of x (ties keep later entry),
//     y carried from the winning position.
//  2) per pixel xin=(s+1)/S (exact fp32 division, matches reference),
//     j = #{k in [1,31] : xin >= xs[k]}.
//  3) out = fmaf(ratio[j], xin - xs[j], ys[j]), ratio = dy / (dx==0 ? 1e-4 : dx).
//
// Key structure: xin is monotone in s, xs is non-decreasing => j(s) is a
// monotone step function. Knots are a running-max of uniforms (~4 distinct
// values), so j is constant over almost every 2048-pixel block. Compute the
// block's [j_lo, j_hi] once via two wave ballots; blocks with j_lo==j_hi
// (the overwhelming majority) take a pure streaming path with no per-element
// segment search.

constexpr int S = 196608;   // 3*256*256
constexpr int NK = 33;      // knots
constexpr int NSEG = 32;
constexpr int BLOCK = 256;
constexpr int EPT = 8;             // elems per thread
constexpr int EPB = BLOCK * EPT;   // 2048 elems per block
constexpr int HALF = BLOCK * 4;    // 1024: two contiguous float4 tiles

__global__ __launch_bounds__(BLOCK) void decoder_kernel(
    const float* __restrict__ seg_x,
    const float* __restrict__ seg_y,
    float* __restrict__ out)
{
    __shared__ float xs[NK];
    __shared__ float ys[NK];
    __shared__ float ratio[NSEG];
    __shared__ int sj[2];

    const int b = blockIdx.y;
    const int tid = threadIdx.x;
    const int p0 = blockIdx.x * EPB;

    // ---- knot prep: wave 0 only, parallel shuffle scan + block j-range ----
    if (tid < 64) {
        float x = 0.0f, y = 0.0f;
        if (tid < NK) {
            x = seg_x[b * NK + tid];
            y = seg_y[b * NK + tid];
        }
        // inclusive running-max scan; later entry wins ties.
#pragma unroll
        for (int d = 1; d < 64; d <<= 1) {
            float ox = __shfl_up(x, d);
            float oy = __shfl_up(y, d);
            if (tid >= d && x < ox) { x = ox; y = oy; }
        }
        float xn = __shfl_down(x, 1);
        float yn = __shfl_down(y, 1);
        if (tid < NK) { xs[tid] = x; ys[tid] = y; }
        if (tid < NSEG) {
            float dx = xn - x;
            if (dx == 0.0f) dx = 0.0001f;
            ratio[tid] = (yn - y) / dx;
        }
        // block-wide segment-index bounds: j monotone in s, xs sorted, so
        // j_lo = j(first pixel of block), j_hi = j(last pixel of block).
        // Exact same fp32 division as the per-element path => exact count.
        const float xin_first = (float)(p0 + 1) / (float)S;
        const float xin_last  = (float)(p0 + EPB) / (float)S;  // (p_last+1)/S
        const bool inseg = (tid >= 1) && (tid < NSEG);  // lane tid holds xs[tid]
        unsigned long long mlo = __ballot(inseg && (xin_first >= x));
        unsigned long long mhi = __ballot(inseg && (xin_last  >= x));
        if (tid == 0) { sj[0] = __popcll(mlo); sj[1] = __popcll(mhi); }
    }
    __syncthreads();

    const int jlo = sj[0];
    const int jhi = sj[1];
    const size_t obase = (size_t)b * S;

    if (jlo == jhi) {
        // ---- fast path (~99% of blocks): single segment covers the block.
        // Bit-identical arithmetic to the general path, j fixed = jlo.
        const float R = ratio[jlo];
        const float X = xs[jlo];
        const float Y = ys[jlo];
#pragma unroll
        for (int h = 0; h < 2; ++h) {
            const int s0 = p0 + h * HALF + tid * 4;
            float4 v;
            v.x = fmaf(R, (float)(s0 + 1) / (float)S - X, Y);
            v.y = fmaf(R, (float)(s0 + 2) / (float)S - X, Y);
            v.z = fmaf(R, (float)(s0 + 3) / (float)S - X, Y);
            v.w = fmaf(R, (float)(s0 + 4) / (float)S - X, Y);
            *reinterpret_cast<float4*>(&out[obase + s0]) = v;  // coalesced 16B
        }
    } else {
        // ---- boundary blocks: count only within (jlo, jhi].
        // For k <= jlo: xs[k] <= xin_first <= xin (always counted).
        // For k >  jhi: xs[k] >  xin_last  >= xin (never counted).
#pragma unroll
        for (int h = 0; h < 2; ++h) {
            const int s0 = p0 + h * HALF + tid * 4;
            float tmp[4];
#pragma unroll
            for (int e = 0; e < 4; ++e) {
                const float xin = (float)(s0 + e + 1) / (float)S;
                int j = jlo;
                for (int k = jlo + 1; k <= jhi; ++k) {
                    j += (xin >= xs[k]) ? 1 : 0;  // LDS broadcast reads
                }
                tmp[e] = fmaf(ratio[j], xin - xs[j], ys[j]);
            }
            float4 v;
            v.x = tmp[0]; v.y = tmp[1]; v.z = tmp[2]; v.w = tmp[3];
            *reinterpret_cast<float4*>(&out[obase + s0]) = v;
        }
    }
}

extern "C" void kernel_launch(void* const* d_in, const int* in_sizes, int n_in,
                              void* d_out, int out_size, void* d_ws, size_t ws_size,
                              hipStream_t stream) {
    const float* seg_x = (const float*)d_in[0];
    const float* seg_y = (const float*)d_in[1];
    float* out = (float*)d_out;

    dim3 grid(S / EPB, 8);  // (96, 8)
    decoder_kernel<<<grid, BLOCK, 0, stream>>>(seg_x, seg_y, out);
}